// Round 10
// baseline (61789.496 us; speedup 1.0000x reference)
//
#include <hip/hip_runtime.h>
#include <math.h>

// Problem dims
#define NBATCH 4096
#define GBLK   32       // worker blocks, 16 hidden cols each
#define HSTR   516      // h_lds row stride in u32 (16B-aligned rows)
#define XSTR   36       // x/bias/attn/M row stride

typedef int   i32x4 __attribute__((ext_vector_type(4)));
typedef float f32x4 __attribute__((ext_vector_type(4)));
typedef short short8 __attribute__((ext_vector_type(8)));

// ws layout (4-byte words) — byte-identical to proven layout
#define OFF_X    0u                         // x[4096][32][28] f32
#define OFF_UA   (OFF_X  + 4096u*896u)      // u_a[4096][28]
#define OFF_BG   (OFF_UA + 4096u*28u)      // fused gate bias [2048]
#define OFF_H    (OFF_BG + 2048u)           // u32 hbuf[2][32][512], packed bf16 hi|lo
#define OFF_BAR  (OFF_H  + 2u*32u*512u)     // flags[64] (use 0..31)
#define OFF_WFH  (OFF_BAR + 64u)            // W frags hi: ((blk8*17+t)*2+ct)*64+lane i32x4
#define OFF_WFL  (OFF_WFH + 557056u)        // W frags lo

// ---- bf16 hi/lo helpers ----
__device__ __forceinline__ unsigned bfr(float x) {
    unsigned u = __builtin_bit_cast(unsigned, x);
    return (u + 0x7FFFu + ((u >> 16) & 1u)) >> 16;
}
__device__ __forceinline__ float fb(unsigned b) { return __builtin_bit_cast(float, b << 16); }
__device__ __forceinline__ unsigned packhl(float v) {
    unsigned h = bfr(v);
    unsigned l = bfr(v - fb(h));
    return h | (l << 16);
}
__device__ __forceinline__ float up(unsigned u) {
    return __builtin_bit_cast(float, u << 16) + __builtin_bit_cast(float, u & 0xFFFF0000u);
}
__device__ __forceinline__ float sigm(float v) { return 1.0f / (1.0f + __expf(-v)); }

// ---------------- Phase 1a: conv1 residual block + u_a (proven) ----------------
__global__ __launch_bounds__(256) void prep_kernel(
    const float* __restrict__ input, const float* __restrict__ masks,
    const float* __restrict__ c1w, const float* __restrict__ c1b,
    const float* __restrict__ convw, const float* __restrict__ convb,
    float* __restrict__ xout, float* __restrict__ uaout)
{
    __shared__ float in_lds[32][28];
    __shared__ float w_lds[28][28][3];
    __shared__ float xo[32][28];
    __shared__ float m_lds[32];
    __shared__ float cb_lds[28];
    const int b = blockIdx.x, tid = threadIdx.x;

    for (int i = tid; i < 896; i += 256) in_lds[i / 28][i % 28] = input[(size_t)b * 896 + i];
    for (int i = tid; i < 2352; i += 256) {
        int o = i / 84, r = i % 84;
        w_lds[o][r / 3][r % 3] = c1w[i];
    }
    if (tid < 32) m_lds[tid] = masks[b * 32 + tid];
    if (tid < 28) cb_lds[tid] = c1b[tid];
    __syncthreads();

    for (int i = tid; i < 896; i += 256) {
        const int l = i / 28, f = i % 28;
        float acc = cb_lds[f];
        for (int ii = 0; ii < 28; ++ii) {
            if (l > 0)  acc = fmaf(in_lds[l - 1][ii], w_lds[f][ii][0], acc);
            acc = fmaf(in_lds[l][ii], w_lds[f][ii][1], acc);
            if (l < 31) acc = fmaf(in_lds[l + 1][ii], w_lds[f][ii][2], acc);
        }
        float v = acc * m_lds[l];
        v = (v > 0.f) ? v : expm1f(v);
        v += in_lds[l][f];
        xo[l][f] = v;
        xout[(size_t)b * 896 + i] = v;
    }
    __syncthreads();
    if (tid < 28) {
        float s = convb[0];
        for (int l = 0; l < 32; ++l) s = fmaf(xo[l][tid], convw[l], s);
        uaout[b * 28 + tid] = s;
    }
}

// ---------------- Phase 1b: fused gate bias ----------------
__global__ __launch_bounds__(256) void prepw_kernel(
    const float* __restrict__ bih, const float* __restrict__ bhh, float* __restrict__ BG)
{
    const int g = blockIdx.x * 256 + threadIdx.x;
    BG[g] = bih[g] + bhh[g];
}

// ---------------- Phase 1c: W -> MFMA B-fragments (proven layout, unchanged) ----------------
__global__ __launch_bounds__(256) void prepf_kernel(
    const float* __restrict__ Wih, const float* __restrict__ Whh,
    unsigned* __restrict__ wfh, unsigned* __restrict__ wfl)
{
    const int id = blockIdx.x * 256 + threadIdx.x;
    const int lane = id & 63;
    int rest = id >> 6;
    const int ct = rest & 1; rest >>= 1;
    const int t = rest % 17, blk8 = rest / 17;
    const int n = lane & 15, kg = lane >> 4;
    const int c = ct * 16 + n;
    const int g = (c >> 3) * 512 + blk8 * 8 + (c & 7);
    const int kbase = t * 32 + kg * 8;
    i32x4 hv, lv;
    #pragma unroll
    for (int d = 0; d < 4; ++d) {
        const int k = kbase + 2 * d;
        float w0 = (k     < 512) ? Whh[(size_t)g * 512 + k]     : Wih[g * 32 + (k - 512)];
        float w1 = (k + 1 < 512) ? Whh[(size_t)g * 512 + k + 1] : Wih[g * 32 + (k + 1 - 512)];
        unsigned h0 = bfr(w0), h1 = bfr(w1);
        unsigned l0 = bfr(w0 - fb(h0)), l1 = bfr(w1 - fb(h1));
        ((unsigned*)&hv)[d] = h0 | (h1 << 16);
        ((unsigned*)&lv)[d] = l0 | (l1 << 16);
    }
    ((i32x4*)wfh)[id] = hv;
    ((i32x4*)wfl)[id] = lv;
}

// ---- single-round-trip h staging (proven r7 form; HSTR=516) ----
__device__ __forceinline__ void stage_h16(const unsigned* hsrc, unsigned* h_lds, int tid)
{
    const int half = tid >> 7, t128 = tid & 127;
    const unsigned* p = hsrc + half * 8192 + t128 * 4;
    i32x4 v0, v1, v2, v3, v4, v5, v6, v7, v8, v9, v10, v11, v12, v13, v14, v15;
    asm volatile(
        "global_load_dwordx4 %0, %16, off sc0 sc1\n\t"
        "global_load_dwordx4 %1, %16, off offset:2048 sc0 sc1\n\t"
        "global_load_dwordx4 %2, %17, off sc0 sc1\n\t"
        "global_load_dwordx4 %3, %17, off offset:2048 sc0 sc1\n\t"
        "global_load_dwordx4 %4, %18, off sc0 sc1\n\t"
        "global_load_dwordx4 %5, %18, off offset:2048 sc0 sc1\n\t"
        "global_load_dwordx4 %6, %19, off sc0 sc1\n\t"
        "global_load_dwordx4 %7, %19, off offset:2048 sc0 sc1\n\t"
        "global_load_dwordx4 %8, %20, off sc0 sc1\n\t"
        "global_load_dwordx4 %9, %20, off offset:2048 sc0 sc1\n\t"
        "global_load_dwordx4 %10, %21, off sc0 sc1\n\t"
        "global_load_dwordx4 %11, %21, off offset:2048 sc0 sc1\n\t"
        "global_load_dwordx4 %12, %22, off sc0 sc1\n\t"
        "global_load_dwordx4 %13, %22, off offset:2048 sc0 sc1\n\t"
        "global_load_dwordx4 %14, %23, off sc0 sc1\n\t"
        "global_load_dwordx4 %15, %23, off offset:2048 sc0 sc1\n\t"
        "s_waitcnt vmcnt(0)"
        : "=&v"(v0), "=&v"(v1), "=&v"(v2), "=&v"(v3),
          "=&v"(v4), "=&v"(v5), "=&v"(v6), "=&v"(v7),
          "=&v"(v8), "=&v"(v9), "=&v"(v10), "=&v"(v11),
          "=&v"(v12), "=&v"(v13), "=&v"(v14), "=&v"(v15)
        : "v"(p), "v"(p + 1024), "v"(p + 2048), "v"(p + 3072),
          "v"(p + 4096), "v"(p + 5120), "v"(p + 6144), "v"(p + 7168)
        : "memory");
    const int col = t128 * 4;
    const int rb = half * 16;
    *(i32x4*)&h_lds[(rb +  0) * HSTR + col] = v0;
    *(i32x4*)&h_lds[(rb +  1) * HSTR + col] = v1;
    *(i32x4*)&h_lds[(rb +  2) * HSTR + col] = v2;
    *(i32x4*)&h_lds[(rb +  3) * HSTR + col] = v3;
    *(i32x4*)&h_lds[(rb +  4) * HSTR + col] = v4;
    *(i32x4*)&h_lds[(rb +  5) * HSTR + col] = v5;
    *(i32x4*)&h_lds[(rb +  6) * HSTR + col] = v6;
    *(i32x4*)&h_lds[(rb +  7) * HSTR + col] = v7;
    *(i32x4*)&h_lds[(rb +  8) * HSTR + col] = v8;
    *(i32x4*)&h_lds[(rb +  9) * HSTR + col] = v9;
    *(i32x4*)&h_lds[(rb + 10) * HSTR + col] = v10;
    *(i32x4*)&h_lds[(rb + 11) * HSTR + col] = v11;
    *(i32x4*)&h_lds[(rb + 12) * HSTR + col] = v12;
    *(i32x4*)&h_lds[(rb + 13) * HSTR + col] = v13;
    *(i32x4*)&h_lds[(rb + 14) * HSTR + col] = v14;
    *(i32x4*)&h_lds[(rb + 15) * HSTR + col] = v15;
}

// wave-level LDS fence (rule #18)
__device__ __forceinline__ void lds_wave_fence()
{
    asm volatile("s_waitcnt lgkmcnt(0)" ::: "memory");
    __builtin_amdgcn_sched_barrier(0);
}

// ---- A/B-fragment build from packed hi|lo u32 (proven) ----
__device__ __forceinline__ void build_frag(const unsigned* base, short8& hi, short8& lo)
{
    i32x4 ua = *(const i32x4*)base;
    i32x4 ub = *(const i32x4*)(base + 4);
    i32x4 h, l;
    h.x = (int)__builtin_amdgcn_perm((unsigned)ua.y, (unsigned)ua.x, 0x05040100u);
    l.x = (int)__builtin_amdgcn_perm((unsigned)ua.y, (unsigned)ua.x, 0x07060302u);
    h.y = (int)__builtin_amdgcn_perm((unsigned)ua.w, (unsigned)ua.z, 0x05040100u);
    l.y = (int)__builtin_amdgcn_perm((unsigned)ua.w, (unsigned)ua.z, 0x07060302u);
    h.z = (int)__builtin_amdgcn_perm((unsigned)ub.y, (unsigned)ub.x, 0x05040100u);
    l.z = (int)__builtin_amdgcn_perm((unsigned)ub.y, (unsigned)ub.x, 0x07060302u);
    h.w = (int)__builtin_amdgcn_perm((unsigned)ub.w, (unsigned)ub.z, 0x05040100u);
    l.w = (int)__builtin_amdgcn_perm((unsigned)ub.w, (unsigned)ub.z, 0x07060302u);
    hi = __builtin_bit_cast(short8, h);
    lo = __builtin_bit_cast(short8, l);
}

// exact out projection (fallback / b<2; cw = global c2w)
__device__ __forceinline__ void out_proj(const unsigned* h_lds, const float* __restrict__ cw,
                                         float c2b, const float* masks, float* out, int bb,
                                         int slot16, int seg16)
{
    float p0 = 0.f, p1 = 0.f;
    #pragma unroll
    for (int jj = 0; jj < 8; ++jj) {
        const int off = seg16 * 4 + 64 * jj;
        f32x4 w = *(const f32x4*)&cw[off];
        i32x4 h0 = *(const i32x4*)&h_lds[slot16 * HSTR + off];
        i32x4 h1 = *(const i32x4*)&h_lds[(slot16 + 16) * HSTR + off];
        p0 += up((unsigned)h0.x) * w.x + up((unsigned)h0.y) * w.y
            + up((unsigned)h0.z) * w.z + up((unsigned)h0.w) * w.w;
        p1 += up((unsigned)h1.x) * w.x + up((unsigned)h1.y) * w.y
            + up((unsigned)h1.z) * w.z + up((unsigned)h1.w) * w.w;
    }
    p0 += __shfl_xor(p0, 1); p0 += __shfl_xor(p0, 2);
    p0 += __shfl_xor(p0, 4); p0 += __shfl_xor(p0, 8);
    p1 += __shfl_xor(p1, 1); p1 += __shfl_xor(p1, 2);
    p1 += __shfl_xor(p1, 4); p1 += __shfl_xor(p1, 8);
    if (seg16 == 0) {
        out[bb * 32 + slot16]      = (p0 + c2b) * masks[bb * 32 + slot16];
        out[bb * 32 + slot16 + 16] = (p1 + c2b) * masks[bb * 32 + slot16 + 16];
    }
}

// ---------------- Phase 2: persistent serial RNN (32 blocks, 3-phase chain) ----------------
__global__ __launch_bounds__(256, 1) void rnn_serial(
    const float* __restrict__ xbuf, const float* __restrict__ uabuf,
    const float* __restrict__ BG,
    const unsigned* __restrict__ wfh, const unsigned* __restrict__ wfl,
    const float* __restrict__ Whh, const float* __restrict__ Wih,
    unsigned* hbuf, int* bar,
    const float* __restrict__ bias_mat, const float* __restrict__ masks,
    const float* __restrict__ fc1w, const float* __restrict__ fc1bp,
    const float* __restrict__ c2w, const float* __restrict__ c2bp,
    float* __restrict__ out)
{
    __shared__ unsigned h_lds[32 * HSTR];      // packed h (512 cols)
    __shared__ float    x_lds[32 * XSTR];      // x(b+1) during step b
    __shared__ float    bias_lds[32 * XSTR];   // bias(b)
    __shared__ unsigned attn_p[2][32 * XSTR];  // per-wave packed attn copies (waves 0,1)
    __shared__ unsigned mpack[2][64 * XSTR];   // M parity buffers, packed bf16 hi|lo
    __shared__ float    wihb[64 * 33];         // block's Wih slice [c][j]
    __shared__ float    glb[4 * 32 * 65];      // bigGEMM partials (4 waves)
    __shared__ float    glm[32 * 65];          // miniGEMM (attn@M) result [l][64 localcol]
    __shared__ float    wapart[4][2][32];      // wa/out K-partials
    __shared__ float    wa_w[2][32];           // per-wave combined wa
    __shared__ float    wa_lds[32];            // exact wa (b<2 / fallback)
    __shared__ float    ua_lds[28];
    __shared__ int      s_flag;

    const int tid  = threadIdx.x;
    const int rank = blockIdx.x;               // 0..31
    const int lane = tid & 63;
    const int wv   = tid >> 6;

    if (tid == 0) s_flag = 0;
    const float f1b = fc1bp[0];
    const float c2b = c2bp[0];

    // ---- gate B-frags: 4 ct tiles (r6/r9-verified map) ----
    i32x4 whi[4][4], wlo[4][4];
    {
        const i32x4* wfh4 = (const i32x4*)wfh;
        const i32x4* wfl4 = (const i32x4*)wfl;
        #pragma unroll
        for (int s = 0; s < 4; ++s)
            #pragma unroll
            for (int ct = 0; ct < 4; ++ct) {
                const int blkOld = 2 * rank + (ct >> 1);
                const int idx = ((blkOld * 17 + wv * 4 + s) * 2 + (ct & 1)) * 64 + lane;
                whi[s][ct] = wfh4[idx];
                wlo[s][ct] = wfl4[idx];
            }
    }
    // wa/out B-frags: col0 = fc1, col1 = c2w (proven r5)
    i32x4 wAh[4], wAl[4];
    {
        const int n = lane & 15, kgi = lane >> 4;
        #pragma unroll
        for (int s = 0; s < 4; ++s) {
            wAh[s] = (i32x4){0, 0, 0, 0};
            wAl[s] = (i32x4){0, 0, 0, 0};
            if (n < 2) {
                const float* src = (n == 0) ? fc1w : c2w;
                const int k0 = (wv * 4 + s) * 32 + kgi * 8;
                #pragma unroll
                for (int d = 0; d < 4; ++d) {
                    float v0 = src[k0 + 2 * d], v1 = src[k0 + 2 * d + 1];
                    unsigned h0 = bfr(v0), h1 = bfr(v1);
                    unsigned l0 = bfr(v0 - fb(h0)), l1 = bfr(v1 - fb(h1));
                    ((unsigned*)&wAh[s])[d] = h0 | (h1 << 16);
                    ((unsigned*)&wAl[s])[d] = l0 | (l1 << 16);
                }
            }
        }
    }

    const int l_own = tid >> 3, hc = tid & 7;     // cells (l_own, hc) and (l_own, hc+8)
    float bgv[2][4];
    #pragma unroll
    for (int j = 0; j < 2; ++j)
        #pragma unroll
        for (int t = 0; t < 4; ++t)
            bgv[j][t] = BG[t * 512 + rank * 16 + hc + 8 * j];
    float creg[2] = {0.f, 0.f};
    bool use_mfma = true;

    const int slot16 = tid >> 4, seg16 = tid & 15;
    const int arow = lane & 15, kg = lane >> 4;

    // ---- prologue: zero pads, load Wih slice, park x(0), M(0) ----
    for (int i = tid; i < 2 * 32 * XSTR; i += 256) attn_p[i / (32 * XSTR)][i % (32 * XSTR)] = 0u;
    for (int i = tid; i < 2 * 64 * XSTR; i += 256) mpack[i / (64 * XSTR)][i % (64 * XSTR)] = 0u;
    for (int i = tid; i < 2048; i += 256) {
        const int c = i >> 5, j = i & 31;
        wihb[c * 33 + j] = Wih[((c >> 4) * 512 + rank * 16 + (c & 15)) * 32 + j];
    }
    if (tid < 224) {
        float4 x0 = *(const float4*)(xbuf + tid * 4);
        #pragma unroll
        for (int i = 0; i < 4; ++i) {
            const int idx = tid * 4 + i;
            const int l = idx / 28, f = idx - l * 28;
            x_lds[l * XSTR + f] = ((const float*)&x0)[i];
        }
    }
    __syncthreads();
    for (int i = tid; i < 1792; i += 256) {
        const int c = i / 28, f = i - c * 28;
        float s = 0.f;
        #pragma unroll 8
        for (int j = 0; j < 32; ++j) s += wihb[c * 33 + j] * x_lds[j * XSTR + f];
        mpack[0][c * XSTR + f] = packhl(s);
    }
    float4 xr = make_float4(0.f, 0.f, 0.f, 0.f), br = xr;
    float ua_r = 0.f;
    if (tid < 224) {
        xr = *(const float4*)(xbuf + 896 + tid * 4);
        br = *(const float4*)(bias_mat + tid * 4);
    }
    if (tid < 28) ua_r = uabuf[tid];
    __syncthreads();

    for (int b = 0; b < NBATCH; ++b) {
        // ---- P0: stage h + park x(b+1)/bias(b)/ua(b) ----
        stage_h16(hbuf + (b & 1) * 16384, h_lds, tid);
        if (tid < 224) {
            #pragma unroll
            for (int i = 0; i < 4; ++i) {
                const int idx = tid * 4 + i;
                const int l = idx / 28, f = idx - l * 28;
                x_lds[l * XSTR + f]    = ((const float*)&xr)[i];
                bias_lds[l * XSTR + f] = ((const float*)&br)[i];
            }
        }
        if (tid < 28) ua_lds[tid] = ua_r;
        __syncthreads();   // S1

        // ---- P1: bigGEMM (K=512) + wa/out cols; M(b+1) VALU overlapped ----
        if (use_mfma) {
            f32x4 accg[4][2], accw[2];
            #pragma unroll
            for (int ct = 0; ct < 4; ++ct) {
                accg[ct][0] = (f32x4){0,0,0,0};
                accg[ct][1] = (f32x4){0,0,0,0};
            }
            accw[0] = (f32x4){0,0,0,0}; accw[1] = (f32x4){0,0,0,0};
            #pragma unroll
            for (int s = 0; s < 4; ++s) {
                const int k0 = (wv * 4 + s) * 32 + kg * 8;
                short8 ah0, al0, ah1, al1;
                build_frag(&h_lds[arow * HSTR + k0], ah0, al0);
                build_frag(&h_lds[(arow + 16) * HSTR + k0], ah1, al1);
                #pragma unroll
                for (int ct = 0; ct < 4; ++ct) {
                    short8 bh = __builtin_bit_cast(short8, whi[s][ct]);
                    short8 bl = __builtin_bit_cast(short8, wlo[s][ct]);
                    accg[ct][0] = __builtin_amdgcn_mfma_f32_16x16x32_bf16(ah0, bh, accg[ct][0], 0, 0, 0);
                    accg[ct][0] = __builtin_amdgcn_mfma_f32_16x16x32_bf16(al0, bh, accg[ct][0], 0, 0, 0);
                    accg[ct][0] = __builtin_amdgcn_mfma_f32_16x16x32_bf16(ah0, bl, accg[ct][0], 0, 0, 0);
                    accg[ct][1] = __builtin_amdgcn_mfma_f32_16x16x32_bf16(ah1, bh, accg[ct][1], 0, 0, 0);
                    accg[ct][1] = __builtin_amdgcn_mfma_f32_16x16x32_bf16(al1, bh, accg[ct][1], 0, 0, 0);
                    accg[ct][1] = __builtin_amdgcn_mfma_f32_16x16x32_bf16(ah1, bl, accg[ct][1], 0, 0, 0);
                }
                short8 bh = __builtin_bit_cast(short8, wAh[s]);
                short8 bl = __builtin_bit_cast(short8, wAl[s]);
                accw[0] = __builtin_amdgcn_mfma_f32_16x16x32_bf16(ah0, bh, accw[0], 0, 0, 0);
                accw[0] = __builtin_amdgcn_mfma_f32_16x16x32_bf16(al0, bh, accw[0], 0, 0, 0);
                accw[0] = __builtin_amdgcn_mfma_f32_16x16x32_bf16(ah0, bl, accw[0], 0, 0, 0);
                accw[1] = __builtin_amdgcn_mfma_f32_16x16x32_bf16(ah1, bh, accw[1], 0, 0, 0);
                accw[1] = __builtin_amdgcn_mfma_f32_16x16x32_bf16(al1, bh, accw[1], 0, 0, 0);
                accw[1] = __builtin_amdgcn_mfma_f32_16x16x32_bf16(ah1, bl, accw[1], 0, 0, 0);
            }
            // M(b+1) = Wih_slice @ x(b+1): VALU, overlaps MFMA drain
            {
                unsigned* mdst = mpack[(b + 1) & 1];
                for (int i = tid; i < 1792; i += 256) {
                    const int c = i / 28, f = i - c * 28;
                    float s = 0.f;
                    #pragma unroll 8
                    for (int j = 0; j < 32; ++j) s += wihb[c * 33 + j] * x_lds[j * XSTR + f];
                    mdst[c * XSTR + f] = packhl(s);
                }
            }
            #pragma unroll
            for (int ct = 0; ct < 4; ++ct)
                #pragma unroll
                for (int rt = 0; rt < 2; ++rt)
                    #pragma unroll
                    for (int r = 0; r < 4; ++r)
                        glb[(wv * 32 + rt * 16 + kg * 4 + r) * 65 + ct * 16 + arow] = accg[ct][rt][r];
            if (arow < 2) {
                #pragma unroll
                for (int rt = 0; rt < 2; ++rt)
                    #pragma unroll
                    for (int r = 0; r < 4; ++r)
                        wapart[wv][arow][rt * 16 + kg * 4 + r] = accw[rt][r];
            }
        } else {
            unsigned* mdst = mpack[(b + 1) & 1];
            for (int i = tid; i < 1792; i += 256) {
                const int c = i / 28, f = i - c * 28;
                float s = 0.f;
                #pragma unroll 8
                for (int j = 0; j < 32; ++j) s += wihb[c * 33 + j] * x_lds[j * XSTR + f];
                mdst[c * XSTR + f] = packhl(s);
            }
        }
        if (b < 2 || !use_mfma) {
            // exact wa + exact out (owner), f32 weights from global (L2-hot)
            float p0 = 0.f, p1 = 0.f;
            #pragma unroll
            for (int jj = 0; jj < 8; ++jj) {
                const int off = seg16 * 4 + 64 * jj;
                f32x4 w = *(const f32x4*)&fc1w[off];
                i32x4 h0 = *(const i32x4*)&h_lds[slot16 * HSTR + off];
                i32x4 h1 = *(const i32x4*)&h_lds[(slot16 + 16) * HSTR + off];
                p0 += up((unsigned)h0.x) * w.x + up((unsigned)h0.y) * w.y
                    + up((unsigned)h0.z) * w.z + up((unsigned)h0.w) * w.w;
                p1 += up((unsigned)h1.x) * w.x + up((unsigned)h1.y) * w.y
                    + up((unsigned)h1.z) * w.z + up((unsigned)h1.w) * w.w;
            }
            p0 += __shfl_xor(p0, 1); p0 += __shfl_xor(p0, 2);
            p0 += __shfl_xor(p0, 4); p0 += __shfl_xor(p0, 8);
            p1 += __shfl_xor(p1, 1); p1 += __shfl_xor(p1, 2);
            p1 += __shfl_xor(p1, 4); p1 += __shfl_xor(p1, 8);
            if (seg16 == 0) { wa_lds[slot16] = p0 + f1b; wa_lds[slot16 + 16] = p1 + f1b; }
            if (b > 0 && rank == ((b - 1) & 31))
                out_proj(h_lds, c2w, c2b, masks, out, b - 1, slot16, seg16);
        }
        // prefetch next step's park regs
        {
            const int bx = (b + 2 < NBATCH) ? b + 2 : NBATCH - 1;
            const int bn = (b + 1 < NBATCH) ? b + 1 : NBATCH - 1;
            if (tid < 224) {
                xr = *(const float4*)(xbuf + (size_t)bx * 896 + tid * 4);
                br = *(const float4*)(bias_mat + (size_t)bn * 896 + tid * 4);
            }
            if (tid < 28) ua_r = uabuf[bn * 28 + tid];
        }
        __syncthreads();   // S2

        // ---- P2: waves 0,1: wa-combine + replicated softmax + miniGEMM (2 ct each);
        //          wave 2: out-combine ----
        if (wv < 2) {
            if (lane < 32) {
                float wm;
                if (use_mfma) {
                    wm = f1b;
                    #pragma unroll
                    for (int w = 0; w < 4; ++w) wm += wapart[w][0][lane];
                    if (b < 2) {
                        if (fabsf(wm - wa_lds[lane]) > 0.02f + 0.004f * fabsf(wa_lds[lane])) s_flag = 1;
                        wm = wa_lds[lane];
                    }
                } else {
                    wm = wa_lds[lane];
                }
                wa_w[wv][lane] = wm;
            }
            lds_wave_fence();
            if (lane < 56) {
                const int f = lane >> 1, hf = lane & 1;
                const float uaf = ua_lds[f];
                float z[16], mx = -1e30f;
                #pragma unroll
                for (int i = 0; i < 16; ++i) {
                    const int l = hf * 16 + i;
                    float v = uaf + wa_w[wv][l];
                    v = (v >= 0.f) ? v : 0.01f * v;
                    v += bias_lds[l * XSTR + f];
                    z[i] = v;
                    mx = fmaxf(mx, v);
                }
                mx = fmaxf(mx, __shfl_xor(mx, 1));
                float sum = 0.f;
                #pragma unroll
                for (int i = 0; i < 16; ++i) { z[i] = __expf(z[i] - mx); sum += z[i]; }
                sum += __shfl_xor(sum, 1);
                const float inv = 1.0f / sum;
                #pragma unroll
                for (int i = 0; i < 16; ++i)
                    attn_p[wv][(hf * 16 + i) * XSTR + f] = packhl(z[i] * inv);
            }
            lds_wave_fence();
            if (use_mfma) {
                short8 ah0, al0, ah1, al1;
                build_frag(&attn_p[wv][arow * XSTR + kg * 8], ah0, al0);
                build_frag(&attn_p[wv][(arow + 16) * XSTR + kg * 8], ah1, al1);
                #pragma unroll
                for (int q = 0; q < 2; ++q) {
                    const int ct = wv * 2 + q;
                    short8 bh, bl;
                    build_frag(&mpack[b & 1][(ct * 16 + arow) * XSTR + kg * 8], bh, bl);
                    f32x4 a0 = (f32x4){0,0,0,0}, a1 = (f32x4){0,0,0,0};
                    a0 = __builtin_amdgcn_mfma_f32_16x16x32_bf16(ah0, bh, a0, 0, 0, 0);
                    a0 = __builtin_amdgcn_mfma_f32_16x16x32_bf16(al0, bh, a0, 0, 0, 0);
                    a0 = __builtin_amdgcn_mfma_f32_16x16x32_bf16(ah0, bl, a0, 0, 0, 0);
                    a1 = __builtin_amdgcn_mfma_f32_16x16x32_bf16(ah1, bh, a1, 0, 0, 0);
                    a1 = __builtin_amdgcn_mfma_f32_16x16x32_bf16(al1, bh, a1, 0, 0, 0);
                    a1 = __builtin_amdgcn_mfma_f32_16x16x32_bf16(ah1, bl, a1, 0, 0, 0);
                    #pragma unroll
                    for (int r = 0; r < 4; ++r) {
                        glm[(     kg * 4 + r) * 65 + ct * 16 + arow] = a0[r];
                        glm[(16 + kg * 4 + r) * 65 + ct * 16 + arow] = a1[r];
                    }
                }
            }
        } else if (wv == 2 && use_mfma && lane < 32) {
            float om = c2b;
            #pragma unroll
            for (int w = 0; w < 4; ++w) om += wapart[w][1][lane];
            if (b < 2) {
                const unsigned* hr = &h_lds[lane * HSTR];
                float ox = c2b;
                for (int k = 0; k < 512; ++k) ox += up(hr[k]) * c2w[k];
                if (fabsf(om - ox) > 0.02f + 0.004f * fabsf(ox)) s_flag = 1;
            } else if (b > 0 && rank == ((b - 1) & 31)) {
                out[(b - 1) * 32 + lane] = om * masks[(b - 1) * 32 + lane];
            }
        }
        __syncthreads();   // S3

        // ---- P3: combine + (b<2 check / fallback) + LSTM (2 cells) + publish ----
        {
            float gv[2][4];
            #pragma unroll
            for (int j = 0; j < 2; ++j)
                #pragma unroll
                for (int t = 0; t < 4; ++t) {
                    float g = bgv[j][t];
                    if (use_mfma) {
                        const int co = (j * 2 + ((t * 8 + hc) >> 4)) * 16 + ((t * 8 + hc) & 15);
                        #pragma unroll
                        for (int w = 0; w < 4; ++w)
                            g += glb[(w * 32 + l_own) * 65 + co];
                        g += glm[l_own * 65 + t * 16 + hc + 8 * j];
                    }
                    gv[j][t] = g;
                }
            if (b < 2 || !use_mfma) {
                const unsigned* hrow = &h_lds[l_own * HSTR];
                const unsigned* ar   = &attn_p[0][l_own * XSTR];
                const unsigned* mb   = mpack[b & 1];
                bool bad = false;
                #pragma unroll
                for (int j = 0; j < 2; ++j)
                    #pragma unroll
                    for (int t = 0; t < 4; ++t) {
                        const int g = t * 512 + rank * 16 + hc + 8 * j;
                        const f32x4* wr = (const f32x4*)(Whh + (size_t)g * 512);
                        float ref = bgv[j][t];
                        #pragma unroll 4
                        for (int q = 0; q < 128; ++q) {
                            f32x4 w = wr[q];
                            ref += up(hrow[4 * q + 0]) * w.x + up(hrow[4 * q + 1]) * w.y
                                 + up(hrow[4 * q + 2]) * w.z + up(hrow[4 * q + 3]) * w.w;
                        }
                        const unsigned* mr = &mb[(t * 16 + hc + 8 * j) * XSTR];
                        #pragma unroll 4
                        for (int f = 0; f < 28; ++f) ref += up(ar[f]) * up(mr[f]);
                        if (b < 2 && use_mfma && fabsf(gv[j][t] - ref) > 0.02f + 0.004f * fabsf(ref)) bad = true;
                        gv[j][t] = ref;
                    }
                if (b < 2) {
                    if (bad) s_flag = 1;
                    __syncthreads();
                    use_mfma = use_mfma && (s_flag == 0);
                    __syncthreads();
                    if (tid == 0) s_flag = 0;
                }
            }
            unsigned* hdst = hbuf + ((b & 1) ^ 1) * 16384 + l_own * 512 + rank * 16 + hc;
            #pragma unroll
            for (int j = 0; j < 2; ++j) {
                const float cn = sigm(gv[j][1]) * creg[j] + sigm(gv[j][0]) * tanhf(gv[j][2]);
                const float hn = sigm(gv[j][3]) * tanhf(cn);
                creg[j] = cn;
                __hip_atomic_store(hdst + 8 * j, packhl(hn),
                                   __ATOMIC_RELAXED, __HIP_MEMORY_SCOPE_AGENT);
            }
        }

        // ---- flag barrier over 32 blocks (proven r5 form) ----
        asm volatile("s_waitcnt vmcnt(0)" ::: "memory");
        __syncthreads();   // S4
        if (tid == 0)
            __hip_atomic_store(&bar[rank], b + 1, __ATOMIC_RELAXED, __HIP_MEMORY_SCOPE_AGENT);
        if (tid < 64) {
            while (true) {
                int v = __hip_atomic_load(&bar[tid & 31], __ATOMIC_RELAXED, __HIP_MEMORY_SCOPE_AGENT);
                if (__all(v >= b + 1)) break;
                __builtin_amdgcn_s_sleep(1);
            }
        }
        __syncthreads();   // S5
    }

    // ---- epilogue: out[4095] from final h (parity 0), owner rank 31 ----
    if (rank == 31) {
        stage_h16(hbuf, h_lds, tid);
        __syncthreads();
        if (use_mfma) {
            f32x4 accw[2];
            accw[0] = (f32x4){0,0,0,0}; accw[1] = (f32x4){0,0,0,0};
            #pragma unroll
            for (int s = 0; s < 4; ++s) {
                const int k0 = (wv * 4 + s) * 32 + kg * 8;
                short8 ah0, al0, ah1, al1;
                build_frag(&h_lds[arow * HSTR + k0], ah0, al0);
                build_frag(&h_lds[(arow + 16) * HSTR + k0], ah1, al1);
                short8 bh = __builtin_bit_cast(short8, wAh[s]);
                short8 bl = __builtin_bit_cast(short8, wAl[s]);
                accw[0] = __builtin_amdgcn_mfma_f32_16x16x32_bf16(ah0, bh, accw[0], 0, 0, 0);
                accw[0] = __builtin_amdgcn_mfma_f32_16x16x32_bf16(al0, bh, accw[0], 0, 0, 0);
                accw[0] = __builtin_amdgcn_mfma_f32_16x16x32_bf16(ah0, bl, accw[0], 0, 0, 0);
                accw[1] = __builtin_amdgcn_mfma_f32_16x16x32_bf16(ah1, bh, accw[1], 0, 0, 0);
                accw[1] = __builtin_amdgcn_mfma_f32_16x16x32_bf16(al1, bh, accw[1], 0, 0, 0);
                accw[1] = __builtin_amdgcn_mfma_f32_16x16x32_bf16(ah1, bl, accw[1], 0, 0, 0);
            }
            if (arow < 2) {
                #pragma unroll
                for (int rt = 0; rt < 2; ++rt)
                    #pragma unroll
                    for (int r = 0; r < 4; ++r)
                        wapart[wv][arow][rt * 16 + kg * 4 + r] = accw[rt][r];
            }
            __syncthreads();
            if (wv == 2 && lane < 32) {
                float om = c2b;
                #pragma unroll
                for (int w = 0; w < 4; ++w) om += wapart[w][1][lane];
                out[4095 * 32 + lane] = om * masks[4095 * 32 + lane];
            }
        } else {
            out_proj(h_lds, c2w, c2b, masks, out, 4095, slot16, seg16);
        }
    }
}

extern "C" void kernel_launch(void* const* d_in, const int* in_sizes, int n_in,
                              void* d_out, int out_size, void* d_ws, size_t ws_size,
                              hipStream_t stream)
{
    const float* input    = (const float*)d_in[0];
    const float* masks    = (const float*)d_in[1];
    const float* bias_mat = (const float*)d_in[2];
    const float* c1w      = (const float*)d_in[3];
    const float* c1b      = (const float*)d_in[4];
    const float* convw    = (const float*)d_in[5];
    const float* convb    = (const float*)d_in[6];
    const float* fc1w     = (const float*)d_in[7];
    const float* fc1b     = (const float*)d_in[8];
    const float* Wih      = (const float*)d_in[9];
    const float* Whh      = (const float*)d_in[10];
    const float* bih      = (const float*)d_in[11];
    const float* bhh      = (const float*)d_in[12];
    const float* c2w      = (const float*)d_in[13];
    const float* c2b      = (const float*)d_in[14];

    float* ws  = (float*)d_ws;
    float* out = (float*)d_out;
    int*   bar = (int*)(ws + OFF_BAR);

    // zero h ping-pong + flags (contiguous; replay-safe each launch)
    hipMemsetAsync(ws + OFF_H, 0, (2u * 32u * 512u + 64u) * sizeof(float), stream);

    hipLaunchKernelGGL(prep_kernel, dim3(NBATCH), dim3(256), 0, stream,
                       input, masks, c1w, c1b, convw, convb, ws + OFF_X, ws + OFF_UA);
    hipLaunchKernelGGL(prepw_kernel, dim3(8), dim3(256), 0, stream,
                       bih, bhh, ws + OFF_BG);
    hipLaunchKernelGGL(prepf_kernel, dim3(544), dim3(256), 0, stream,
                       Wih, Whh, (unsigned*)(ws + OFF_WFH), (unsigned*)(ws + OFF_WFL));
    hipLaunchKernelGGL(rnn_serial, dim3(GBLK), dim3(256), 0, stream,
                       ws + OFF_X, ws + OFF_UA, ws + OFF_BG,
                       (const unsigned*)(ws + OFF_WFH), (const unsigned*)(ws + OFF_WFL),
                       Whh, Wih,
                       (unsigned*)(ws + OFF_H), bar,
                       bias_mat, masks, fc1w, fc1b, c2w, c2b, out);
}

// Round 11
// 28794.217 us; speedup vs baseline: 2.1459x; 2.1459x over previous
//
#include <hip/hip_runtime.h>
#include <math.h>

// Problem dims
#define NBATCH 4096
#define LSEQ   32
#define FDIM   28
#define HDIM   512
#define GBLK   64       // worker blocks (8 gate-cols each => 32 gate cols w/ 4 gates)
#define SLICE  8
#define HSTRIDE 548     // h_lds row stride in u32 (row base 16B aligned: 548*4=2192=137*16)
#define XSTR    36

typedef int   i32x4 __attribute__((ext_vector_type(4)));
typedef float f32x4 __attribute__((ext_vector_type(4)));
typedef short short8 __attribute__((ext_vector_type(8)));

// ws layout (4-byte words). TOTAL = 4,933,696 words = 19,734,784 B (proven size)
#define OFF_X    0u                         // x[4096][32][28] f32
#define OFF_UA   (OFF_X  + 4096u*896u)      // u_a[4096][28]
#define OFF_BG   (OFF_UA + 4096u*28u)       // fused gate bias [2048]
#define OFF_H    (OFF_BG + 2048u)           // u32 hbuf[2][32][512], packed bf16 hi|lo
#define OFF_BAR  (OFF_H  + 2u*32u*512u)     // barrier ints (64 words)
#define OFF_WFH  (OFF_BAR + 64u)            // W frags hi: 64blk*17t*2ct*64lane i32x4 = 557056 w
#define OFF_WFL  (OFF_WFH + 557056u)        // W frags lo: 557056 w

// ---- bf16 hi/lo helpers ----
__device__ __forceinline__ unsigned bfr(float x) {            // f32 -> bf16 bits (RNE)
    unsigned u = __builtin_bit_cast(unsigned, x);
    return (u + 0x7FFFu + ((u >> 16) & 1u)) >> 16;
}
__device__ __forceinline__ float fb(unsigned b) { return __builtin_bit_cast(float, b << 16); }
__device__ __forceinline__ unsigned packhl(float v) {          // hi in [15:0], lo in [31:16]
    unsigned h = bfr(v);
    unsigned l = bfr(v - fb(h));
    return h | (l << 16);
}
__device__ __forceinline__ float up(unsigned u) {              // unpack hi+lo -> ~f32
    return __builtin_bit_cast(float, u << 16) + __builtin_bit_cast(float, u & 0xFFFF0000u);
}
__device__ __forceinline__ float sigm(float v) { return 1.0f / (1.0f + __expf(-v)); }

// ---------------- Phase 1a: conv1 residual block + u_a (proven) ----------------
__global__ __launch_bounds__(256) void prep_kernel(
    const float* __restrict__ input, const float* __restrict__ masks,
    const float* __restrict__ c1w, const float* __restrict__ c1b,
    const float* __restrict__ convw, const float* __restrict__ convb,
    float* __restrict__ xout, float* __restrict__ uaout)
{
    __shared__ float in_lds[32][28];
    __shared__ float w_lds[28][28][3];
    __shared__ float xo[32][28];
    __shared__ float m_lds[32];
    __shared__ float cb_lds[28];
    const int b = blockIdx.x, tid = threadIdx.x;

    for (int i = tid; i < 896; i += 256) in_lds[i / 28][i % 28] = input[(size_t)b * 896 + i];
    for (int i = tid; i < 2352; i += 256) {
        int o = i / 84, r = i % 84;
        w_lds[o][r / 3][r % 3] = c1w[i];
    }
    if (tid < 32) m_lds[tid] = masks[b * 32 + tid];
    if (tid < 28) cb_lds[tid] = c1b[tid];
    __syncthreads();

    for (int i = tid; i < 896; i += 256) {
        const int l = i / 28, f = i % 28;
        float acc = cb_lds[f];
        for (int ii = 0; ii < 28; ++ii) {
            if (l > 0)  acc = fmaf(in_lds[l - 1][ii], w_lds[f][ii][0], acc);
            acc = fmaf(in_lds[l][ii], w_lds[f][ii][1], acc);
            if (l < 31) acc = fmaf(in_lds[l + 1][ii], w_lds[f][ii][2], acc);
        }
        float v = acc * m_lds[l];
        v = (v > 0.f) ? v : expm1f(v);   // ELU
        v += in_lds[l][f];               // residual
        xo[l][f] = v;
        xout[(size_t)b * 896 + i] = v;
    }
    __syncthreads();
    if (tid < 28) {
        float s = convb[0];
        for (int l = 0; l < 32; ++l) s = fmaf(xo[l][tid], convw[l], s);
        uaout[b * 28 + tid] = s;
    }
}

// ---------------- Phase 1b: fused gate bias ----------------
__global__ __launch_bounds__(256) void prepw_kernel(
    const float* __restrict__ bih, const float* __restrict__ bhh, float* __restrict__ BG)
{
    const int g = blockIdx.x * 256 + threadIdx.x;
    BG[g] = bih[g] + bhh[g];
}

// ---------------- Phase 1c: W -> MFMA B-fragments, bf16 hi/lo split ----------------
// frag idx = ((blk*17 + t)*2 + ct)*64 + lane (each i32x4).
// Lane holds B[k][n]: n = lane&15, k = t*32 + (lane>>4)*8 + e (e=0..7, even e in low half).
// Local col c = ct*16 + n; gate tg = c>>3; hc = c&7; global g = tg*512 + blk*8 + hc.
__global__ __launch_bounds__(256) void prepf_kernel(
    const float* __restrict__ Wih, const float* __restrict__ Whh,
    unsigned* __restrict__ wfh, unsigned* __restrict__ wfl)
{
    const int id = blockIdx.x * 256 + threadIdx.x;   // 0..139263
    const int lane = id & 63;
    int rest = id >> 6;
    const int ct = rest & 1; rest >>= 1;
    const int t = rest % 17, blk = rest / 17;
    const int n = lane & 15, kg = lane >> 4;
    const int c = ct * 16 + n;
    const int g = (c >> 3) * 512 + blk * 8 + (c & 7);
    const int kbase = t * 32 + kg * 8;
    i32x4 hv, lv;
    #pragma unroll
    for (int d = 0; d < 4; ++d) {
        const int k = kbase + 2 * d;
        float w0 = (k     < 512) ? Whh[(size_t)g * 512 + k]     : Wih[g * 32 + (k - 512)];
        float w1 = (k + 1 < 512) ? Whh[(size_t)g * 512 + k + 1] : Wih[g * 32 + (k + 1 - 512)];
        unsigned h0 = bfr(w0), h1 = bfr(w1);
        unsigned l0 = bfr(w0 - fb(h0)), l1 = bfr(w1 - fb(h1));
        ((unsigned*)&hv)[d] = h0 | (h1 << 16);
        ((unsigned*)&lv)[d] = l0 | (l1 << 16);
    }
    ((i32x4*)wfh)[id] = hv;
    ((i32x4*)wfl)[id] = lv;
}

// ---- pipelined device-scope h staging: 8 dwordx4 in flight, ONE waitcnt ----
__device__ __forceinline__ void stage8(const unsigned* p, unsigned* h_lds, int tid, int r)
{
    i32x4 v0, v1, v2, v3, v4, v5, v6, v7;
    asm volatile(
        "global_load_dwordx4 %0, %8, off sc0 sc1\n\t"
        "global_load_dwordx4 %1, %9, off sc0 sc1\n\t"
        "global_load_dwordx4 %2, %10, off sc0 sc1\n\t"
        "global_load_dwordx4 %3, %11, off sc0 sc1\n\t"
        "global_load_dwordx4 %4, %12, off sc0 sc1\n\t"
        "global_load_dwordx4 %5, %13, off sc0 sc1\n\t"
        "global_load_dwordx4 %6, %14, off sc0 sc1\n\t"
        "global_load_dwordx4 %7, %15, off sc0 sc1\n\t"
        "s_waitcnt vmcnt(0)"
        : "=&v"(v0), "=&v"(v1), "=&v"(v2), "=&v"(v3),
          "=&v"(v4), "=&v"(v5), "=&v"(v6), "=&v"(v7)
        : "v"(p), "v"(p + 1024), "v"(p + 2048), "v"(p + 3072),
          "v"(p + 4096), "v"(p + 5120), "v"(p + 6144), "v"(p + 7168)
        : "memory");
    const int col = (tid & 127) * 4;
    const int rb = 16 * r + (tid >> 7);
    *(i32x4*)&h_lds[(rb +  0) * HSTRIDE + col] = v0;
    *(i32x4*)&h_lds[(rb +  2) * HSTRIDE + col] = v1;
    *(i32x4*)&h_lds[(rb +  4) * HSTRIDE + col] = v2;
    *(i32x4*)&h_lds[(rb +  6) * HSTRIDE + col] = v3;
    *(i32x4*)&h_lds[(rb +  8) * HSTRIDE + col] = v4;
    *(i32x4*)&h_lds[(rb + 10) * HSTRIDE + col] = v5;
    *(i32x4*)&h_lds[(rb + 12) * HSTRIDE + col] = v6;
    *(i32x4*)&h_lds[(rb + 14) * HSTRIDE + col] = v7;
}
__device__ __forceinline__ void stage_h(const unsigned* hsrc, unsigned* h_lds, int tid)
{
    stage8(hsrc + tid * 4,        h_lds, tid, 0);
    stage8(hsrc + tid * 4 + 8192, h_lds, tid, 1);
}

// ---- A-fragment build: 8 packed u32 (k..k+7) -> (hi, lo) short8 via v_perm ----
__device__ __forceinline__ void build_frag(const unsigned* base, short8& hi, short8& lo)
{
    i32x4 ua = *(const i32x4*)base;
    i32x4 ub = *(const i32x4*)(base + 4);
    i32x4 h, l;
    h.x = (int)__builtin_amdgcn_perm((unsigned)ua.y, (unsigned)ua.x, 0x05040100u);
    l.x = (int)__builtin_amdgcn_perm((unsigned)ua.y, (unsigned)ua.x, 0x07060302u);
    h.y = (int)__builtin_amdgcn_perm((unsigned)ua.w, (unsigned)ua.z, 0x05040100u);
    l.y = (int)__builtin_amdgcn_perm((unsigned)ua.w, (unsigned)ua.z, 0x07060302u);
    h.z = (int)__builtin_amdgcn_perm((unsigned)ub.y, (unsigned)ub.x, 0x05040100u);
    l.z = (int)__builtin_amdgcn_perm((unsigned)ub.y, (unsigned)ub.x, 0x07060302u);
    h.w = (int)__builtin_amdgcn_perm((unsigned)ub.w, (unsigned)ub.z, 0x05040100u);
    l.w = (int)__builtin_amdgcn_perm((unsigned)ub.w, (unsigned)ub.z, 0x07060302u);
    hi = __builtin_bit_cast(short8, h);
    lo = __builtin_bit_cast(short8, l);
}

// exact f32 gate dot (self-check + fallback): reads original Whh/Wih from d_in
__device__ __forceinline__ float exact_gate(const unsigned* hrow,
    const float* __restrict__ Whh, const float* __restrict__ Wih, int g)
{
    const f32x4* wr = (const f32x4*)(Whh + (size_t)g * 512);
    float s = 0.f;
    #pragma unroll 4
    for (int q = 0; q < 128; ++q) {
        f32x4 w = wr[q];
        s += up(hrow[4 * q + 0]) * w.x + up(hrow[4 * q + 1]) * w.y
           + up(hrow[4 * q + 2]) * w.z + up(hrow[4 * q + 3]) * w.w;
    }
    const float* wi = Wih + g * 32;
    #pragma unroll 8
    for (int j = 0; j < 32; ++j) s += up(hrow[512 + j]) * wi[j];
    return s;
}

// out projection for batch bb from staged h (rows via slot16, u32 packed)
__device__ __forceinline__ void out_proj(const unsigned* h_lds, const float* c2w_lds, float c2b,
                                         const float* masks, float* out, int bb,
                                         int slot16, int seg16)
{
    float p0 = 0.f, p1 = 0.f;
    #pragma unroll
    for (int jj = 0; jj < 8; ++jj) {
        const int off = seg16 * 4 + 64 * jj;
        f32x4 w = *(const f32x4*)&c2w_lds[off];
        i32x4 h0 = *(const i32x4*)&h_lds[slot16 * HSTRIDE + off];
        i32x4 h1 = *(const i32x4*)&h_lds[(slot16 + 16) * HSTRIDE + off];
        p0 += up((unsigned)h0.x) * w.x + up((unsigned)h0.y) * w.y
            + up((unsigned)h0.z) * w.z + up((unsigned)h0.w) * w.w;
        p1 += up((unsigned)h1.x) * w.x + up((unsigned)h1.y) * w.y
            + up((unsigned)h1.z) * w.z + up((unsigned)h1.w) * w.w;
    }
    p0 += __shfl_xor(p0, 1); p0 += __shfl_xor(p0, 2);
    p0 += __shfl_xor(p0, 4); p0 += __shfl_xor(p0, 8);
    p1 += __shfl_xor(p1, 1); p1 += __shfl_xor(p1, 2);
    p1 += __shfl_xor(p1, 4); p1 += __shfl_xor(p1, 8);
    if (seg16 == 0) {
        out[bb * 32 + slot16]      = (p0 + c2b) * masks[bb * 32 + slot16];
        out[bb * 32 + slot16 + 16] = (p1 + c2b) * masks[bb * 32 + slot16 + 16];
    }
}

// ---------------- Phase 2: persistent serial RNN (64 blocks, proven barrier) ----------------
__global__ __launch_bounds__(256, 1) void rnn_serial(
    const float* __restrict__ xbuf, const float* __restrict__ uabuf,
    const float* __restrict__ BG,
    const unsigned* __restrict__ wfh, const unsigned* __restrict__ wfl,
    const float* __restrict__ Whh, const float* __restrict__ Wih,
    unsigned* hbuf, int* bar,
    const float* __restrict__ bias_mat, const float* __restrict__ masks,
    const float* __restrict__ fc1w, const float* __restrict__ fc1bp,
    const float* __restrict__ c2w, const float* __restrict__ c2bp,
    float* __restrict__ out)
{
    __shared__ unsigned h_lds[32 * HSTRIDE];   // packed h (0..511) + ctx (512..543)
    __shared__ float x_lds[32 * XSTR];
    __shared__ float bias_lds[32 * XSTR];
    __shared__ float attn_lds[32 * XSTR];
    __shared__ float gl_part[4 * 32 * 33];     // per-wave gate partials
    __shared__ float wa_lds[32];
    __shared__ float ua_lds[28];
    __shared__ float fc1_lds[512];
    __shared__ float c2w_lds[512];
    __shared__ int   s_flag;

    const int tid  = threadIdx.x;
    const int blk  = blockIdx.x;
    const int lane = tid & 63;
    const int wv   = tid >> 6;

    for (int i = tid; i < 512; i += 256) { fc1_lds[i] = fc1w[i]; c2w_lds[i] = c2w[i]; }
    if (tid == 0) s_flag = 0;
    const float f1b = fc1bp[0];
    const float c2b = c2bp[0];

    // ---- W MFMA fragments resident in registers: wave wv owns k-tiles t0..t0+nt-1 ----
    const int nt = (wv < 3) ? 4 : 5;
    const int t0 = (wv < 3) ? wv * 4 : 12;
    i32x4 whi[5][2], wlo[5][2];
    {
        const i32x4* wfh4 = (const i32x4*)wfh;
        const i32x4* wfl4 = (const i32x4*)wfl;
        for (int s = 0; s < 5; ++s) {
            if (s < nt) {
                #pragma unroll
                for (int ct = 0; ct < 2; ++ct) {
                    const int idx = ((blk * 17 + t0 + s) * 2 + ct) * 64 + lane;
                    whi[s][ct] = wfh4[idx];
                    wlo[s][ct] = wfl4[idx];
                }
            }
        }
    }

    const int l_own = tid >> 3, hc = tid & 7;      // owned LSTM cell (l_own, blk*8+hc)
    float bgv[4];
    #pragma unroll
    for (int t = 0; t < 4; ++t) bgv[t] = BG[t * 512 + blk * 8 + hc];
    float c_reg = 0.f;
    bool use_mfma = true;

    // prefetch x/bias/ua for b=0
    float4 xr = make_float4(0.f, 0.f, 0.f, 0.f), br = xr;
    float ua_r = 0.f;
    if (tid < 224) {
        xr = *(const float4*)(xbuf + tid * 4);
        br = *(const float4*)(bias_mat + tid * 4);
    }
    if (tid < 28) ua_r = uabuf[tid];

    const int slot16 = tid >> 4, seg16 = tid & 15;
    const int arow = lane & 15, kg = lane >> 4;
    int* cnt = bar;
    __syncthreads();

    for (int b = 0; b < NBATCH; ++b) {
        // ---- phase 1: stage h (pipelined, device-scope) + park x/bias/ua ----
        stage_h(hbuf + (b & 1) * 16384, h_lds, tid);
        if (tid < 224) {
            #pragma unroll
            for (int i = 0; i < 4; ++i) {
                const int idx = tid * 4 + i;
                const int l = idx / 28, f = idx - l * 28;
                x_lds[l * XSTR + f]    = ((const float*)&xr)[i];
                bias_lds[l * XSTR + f] = ((const float*)&br)[i];
            }
        }
        if (tid < 28) ua_lds[tid] = ua_r;
        __syncthreads();

        // ---- phase 2: w_a[l] = h[l,:512] . fc1 ; rotating out_proj(b-1) ----
        {
            float p0 = 0.f, p1 = 0.f;
            #pragma unroll
            for (int jj = 0; jj < 8; ++jj) {
                const int off = seg16 * 4 + 64 * jj;
                f32x4 w = *(const f32x4*)&fc1_lds[off];
                i32x4 h0 = *(const i32x4*)&h_lds[slot16 * HSTRIDE + off];
                i32x4 h1 = *(const i32x4*)&h_lds[(slot16 + 16) * HSTRIDE + off];
                p0 += up((unsigned)h0.x) * w.x + up((unsigned)h0.y) * w.y
                    + up((unsigned)h0.z) * w.z + up((unsigned)h0.w) * w.w;
                p1 += up((unsigned)h1.x) * w.x + up((unsigned)h1.y) * w.y
                    + up((unsigned)h1.z) * w.z + up((unsigned)h1.w) * w.w;
            }
            p0 += __shfl_xor(p0, 1); p0 += __shfl_xor(p0, 2);
            p0 += __shfl_xor(p0, 4); p0 += __shfl_xor(p0, 8);
            p1 += __shfl_xor(p1, 1); p1 += __shfl_xor(p1, 2);
            p1 += __shfl_xor(p1, 4); p1 += __shfl_xor(p1, 8);
            if (seg16 == 0) { wa_lds[slot16] = p0 + f1b; wa_lds[slot16 + 16] = p1 + f1b; }
        }
        if (b > 0 && blk == ((b - 1) & 63))
            out_proj(h_lds, c2w_lds, c2b, masks, out, b - 1, slot16, seg16);
        __syncthreads();

        // ---- phase 3: softmax over l per feature f ----
        if (tid < 224) {
            const int f = tid >> 3, ls = tid & 7;
            const float uaf = ua_lds[f];
            float z[4];
            #pragma unroll
            for (int r = 0; r < 4; ++r) {
                const int l = ls + 8 * r;
                float v = uaf + wa_lds[l];
                v = (v >= 0.f) ? v : 0.01f * v;      // leaky_relu 0.01
                z[r] = v + bias_lds[l * XSTR + f];
            }
            float mx = fmaxf(fmaxf(z[0], z[1]), fmaxf(z[2], z[3]));
            mx = fmaxf(mx, __shfl_xor(mx, 1));
            mx = fmaxf(mx, __shfl_xor(mx, 2));
            mx = fmaxf(mx, __shfl_xor(mx, 4));
            float s = 0.f;
            #pragma unroll
            for (int r = 0; r < 4; ++r) { z[r] = __expf(z[r] - mx); s += z[r]; }
            s += __shfl_xor(s, 1); s += __shfl_xor(s, 2); s += __shfl_xor(s, 4);
            const float inv = 1.0f / s;
            #pragma unroll
            for (int r = 0; r < 4; ++r) attn_lds[(ls + 8 * r) * XSTR + f] = z[r] * inv;
        }
        __syncthreads();

        // ---- phase 4: ctx -> h_lds cols 512..543 (packed); prefetch next x/bias/ua ----
        {
            const int j0 = hc * 4;
            float t0v = 0.f, t1v = 0.f, t2v = 0.f, t3v = 0.f;
            #pragma unroll
            for (int fo = 0; fo < 7; ++fo) {
                f32x4 a4 = *(const f32x4*)&attn_lds[l_own * XSTR + fo * 4];
                f32x4 x0 = *(const f32x4*)&x_lds[(j0 + 0) * XSTR + fo * 4];
                f32x4 x1 = *(const f32x4*)&x_lds[(j0 + 1) * XSTR + fo * 4];
                f32x4 x2 = *(const f32x4*)&x_lds[(j0 + 2) * XSTR + fo * 4];
                f32x4 x3 = *(const f32x4*)&x_lds[(j0 + 3) * XSTR + fo * 4];
                t0v += a4.x * x0.x + a4.y * x0.y + a4.z * x0.z + a4.w * x0.w;
                t1v += a4.x * x1.x + a4.y * x1.y + a4.z * x1.z + a4.w * x1.w;
                t2v += a4.x * x2.x + a4.y * x2.y + a4.z * x2.z + a4.w * x2.w;
                t3v += a4.x * x3.x + a4.y * x3.y + a4.z * x3.z + a4.w * x3.w;
            }
            i32x4 cp;
            cp.x = (int)packhl(t0v); cp.y = (int)packhl(t1v);
            cp.z = (int)packhl(t2v); cp.w = (int)packhl(t3v);
            *(i32x4*)&h_lds[l_own * HSTRIDE + 512 + j0] = cp;
        }
        {
            const int bn = (b + 1 < NBATCH) ? b + 1 : 0;
            if (tid < 224) {
                xr = *(const float4*)(xbuf + (size_t)bn * 896 + tid * 4);
                br = *(const float4*)(bias_mat + (size_t)bn * 896 + tid * 4);
            }
            if (tid < 28) ua_r = uabuf[bn * 28 + tid];
        }
        __syncthreads();

        // ---- phase 5: gate GEMM via MFMA; waves split K (tiles t0..t0+nt-1) ----
        if (use_mfma) {
            f32x4 acc[2][2];
            acc[0][0] = (f32x4){0,0,0,0}; acc[0][1] = (f32x4){0,0,0,0};
            acc[1][0] = (f32x4){0,0,0,0}; acc[1][1] = (f32x4){0,0,0,0};
            #pragma unroll
            for (int s = 0; s < 5; ++s) {
                if (s < nt) {
                    const int k0 = (t0 + s) * 32 + kg * 8;
                    short8 ah0, al0, ah1, al1;
                    build_frag(&h_lds[arow * HSTRIDE + k0], ah0, al0);
                    build_frag(&h_lds[(arow + 16) * HSTRIDE + k0], ah1, al1);
                    #pragma unroll
                    for (int ct = 0; ct < 2; ++ct) {
                        short8 bh = __builtin_bit_cast(short8, whi[s][ct]);
                        short8 bl = __builtin_bit_cast(short8, wlo[s][ct]);
                        acc[ct][0] = __builtin_amdgcn_mfma_f32_16x16x32_bf16(ah0, bh, acc[ct][0], 0, 0, 0);
                        acc[ct][0] = __builtin_amdgcn_mfma_f32_16x16x32_bf16(al0, bh, acc[ct][0], 0, 0, 0);
                        acc[ct][0] = __builtin_amdgcn_mfma_f32_16x16x32_bf16(ah0, bl, acc[ct][0], 0, 0, 0);
                        acc[ct][1] = __builtin_amdgcn_mfma_f32_16x16x32_bf16(ah1, bh, acc[ct][1], 0, 0, 0);
                        acc[ct][1] = __builtin_amdgcn_mfma_f32_16x16x32_bf16(al1, bh, acc[ct][1], 0, 0, 0);
                        acc[ct][1] = __builtin_amdgcn_mfma_f32_16x16x32_bf16(ah1, bl, acc[ct][1], 0, 0, 0);
                    }
                }
            }
            // C/D layout (m89-verified): col = lane&15, row = (lane>>4)*4 + reg
            #pragma unroll
            for (int ct = 0; ct < 2; ++ct)
                #pragma unroll
                for (int rt = 0; rt < 2; ++rt)
                    #pragma unroll
                    for (int r = 0; r < 4; ++r) {
                        const int row = rt * 16 + (lane >> 4) * 4 + r;
                        gl_part[(wv * 32 + row) * 33 + ct * 16 + (lane & 15)] = acc[ct][rt][r];
                    }
        }
        __syncthreads();

        // ---- phase 6: combine + (b<2 self-check / fallback) + LSTM + publish ----
        {
            float gv[4];
            #pragma unroll
            for (int t = 0; t < 4; ++t) {
                float g = bgv[t];
                if (use_mfma) {
                    #pragma unroll
                    for (int w = 0; w < 4; ++w)
                        g += gl_part[(w * 32 + l_own) * 33 + t * 8 + hc];
                }
                gv[t] = g;
            }
            if (b < 2) {
                bool bad = false;
                #pragma unroll
                for (int t = 0; t < 4; ++t) {
                    float ref = bgv[t] + exact_gate(&h_lds[l_own * HSTRIDE], Whh, Wih,
                                                    t * 512 + blk * 8 + hc);
                    if (use_mfma && fabsf(gv[t] - ref) > 0.02f + 0.004f * fabsf(ref)) bad = true;
                    gv[t] = ref;
                }
                if (bad) s_flag = 1;
                __syncthreads();
                use_mfma = use_mfma && (s_flag == 0);
                __syncthreads();
                if (tid == 0) s_flag = 0;
            } else if (!use_mfma) {
                #pragma unroll
                for (int t = 0; t < 4; ++t)
                    gv[t] = bgv[t] + exact_gate(&h_lds[l_own * HSTRIDE], Whh, Wih,
                                                t * 512 + blk * 8 + hc);
            }
            const float cn = sigm(gv[1]) * c_reg + sigm(gv[0]) * tanhf(gv[2]);
            const float hn = sigm(gv[3]) * tanhf(cn);
            c_reg = cn;
            __hip_atomic_store(hbuf + ((b & 1) ^ 1) * 16384 + l_own * 512 + blk * 8 + hc,
                               packhl(hn), __ATOMIC_RELAXED, __HIP_MEMORY_SCOPE_AGENT);
        }

        // ---- phase 7: grid barrier (proven round-2 form) ----
        asm volatile("s_waitcnt vmcnt(0)" ::: "memory");
        __syncthreads();
        if (tid == 0) {
            __hip_atomic_fetch_add(cnt, 1, __ATOMIC_RELAXED, __HIP_MEMORY_SCOPE_AGENT);
            const int target = (b + 1) * GBLK;
            while (__hip_atomic_load(cnt, __ATOMIC_RELAXED, __HIP_MEMORY_SCOPE_AGENT) < target)
                __builtin_amdgcn_s_sleep(1);
        }
        __syncthreads();
    }

    // final output row: h after batch 4095 lives in hbuf[0]
    if (blk == 0) {
        stage_h(hbuf, h_lds, tid);
        __syncthreads();
        out_proj(h_lds, c2w_lds, c2b, masks, out, NBATCH - 1, slot16, seg16);
    }
}

extern "C" void kernel_launch(void* const* d_in, const int* in_sizes, int n_in,
                              void* d_out, int out_size, void* d_ws, size_t ws_size,
                              hipStream_t stream)
{
    const float* input    = (const float*)d_in[0];
    const float* masks    = (const float*)d_in[1];
    const float* bias_mat = (const float*)d_in[2];
    const float* c1w      = (const float*)d_in[3];
    const float* c1b      = (const float*)d_in[4];
    const float* convw    = (const float*)d_in[5];
    const float* convb    = (const float*)d_in[6];
    const float* fc1w     = (const float*)d_in[7];
    const float* fc1b     = (const float*)d_in[8];
    const float* Wih      = (const float*)d_in[9];
    const float* Whh      = (const float*)d_in[10];
    const float* bih      = (const float*)d_in[11];
    const float* bhh      = (const float*)d_in[12];
    const float* c2w      = (const float*)d_in[13];
    const float* c2b      = (const float*)d_in[14];

    float* ws  = (float*)d_ws;
    float* out = (float*)d_out;
    int*   bar = (int*)(ws + OFF_BAR);

    // zero h ping-pong + barrier (contiguous region; replay-safe each launch)
    hipMemsetAsync(ws + OFF_H, 0, (2u * 32u * 512u + 64u) * sizeof(float), stream);

    hipLaunchKernelGGL(prep_kernel, dim3(NBATCH), dim3(256), 0, stream,
                       input, masks, c1w, c1b, convw, convb, ws + OFF_X, ws + OFF_UA);
    hipLaunchKernelGGL(prepw_kernel, dim3(8), dim3(256), 0, stream,
                       bih, bhh, ws + OFF_BG);
    hipLaunchKernelGGL(prepf_kernel, dim3(544), dim3(256), 0, stream,
                       Wih, Whh, (unsigned*)(ws + OFF_WFH), (unsigned*)(ws + OFF_WFL));
    hipLaunchKernelGGL(rnn_serial, dim3(GBLK), dim3(256), 0, stream,
                       ws + OFF_X, ws + OFF_UA, ws + OFF_BG,
                       (const unsigned*)(ws + OFF_WFH), (const unsigned*)(ws + OFF_WFL),
                       Whh, Wih,
                       (unsigned*)(ws + OFF_H), bar,
                       bias_mat, masks, fc1w, fc1b, c2w, c2b, out);
}